// Round 9
// baseline (1331.013 us; speedup 1.0000x reference)
//
#include <hip/hip_runtime.h>
#include <hip/hip_bf16.h>
#include <math.h>

typedef __hip_bfloat16 bf16;
typedef __bf16 bf16x8 __attribute__((ext_vector_type(8)));
typedef float f32x4 __attribute__((ext_vector_type(4)));

#define NDEPTH 4
#define DIM 768
#define HEADS 12
#define DH 64
#define INNER 768
#define FFI 2048
#define BB 4
#define NN 1024
#define ROWS (BB*NN)   // 4096

__device__ __forceinline__ void async_cp16(const bf16* g, bf16* l) {
  __builtin_amdgcn_global_load_lds(
      (const __attribute__((address_space(1))) unsigned int*)g,
      (__attribute__((address_space(3))) unsigned int*)l, 16, 0, 0);
}

// ---------------------------------------------------------------------------
// bf16 MFMA GEMM body (R1 config — measured best for the N<=1536 GEMMs).
// C[MxN] = A[MxK] @ Bt[NxK]^T. 128xBN tile, BK=64, 4 waves, XOR-swizzled LDS
// (0 bank conflicts measured). 2-phase double-buffered pipeline: stage next
// K-tile before computing current; one __syncthreads per step.
// GEMM-plateau history: depth-2/3-buffer (R2), 1D XCD swizzle (R3), BK=32
// (R4), 256^2 2ph (R5), 8-phase counted-vmcnt (R7/R8 — conflicts fixed to 0,
// still null) ALL land at ~500 TF for these K<=2048 shapes. Plateau is
// structural (small-K amortization); R9 strategy = remove work, not schedule.
// Rf: fused residual add (f32); Cf/Cb: f32/bf16 outputs.
// ---------------------------------------------------------------------------
template<int BN, bool GELU, bool VOUT, int K, int LD>
__device__ __forceinline__ void gemm_body(
    const bf16* __restrict__ A, const bf16* __restrict__ Bt,
    bf16* __restrict__ Cb, float* __restrict__ Cf, const float* __restrict__ Rf,
    bf16* __restrict__ Vt, int M, int N, int bx, int by, bf16* As, bf16* Bs)
{
  constexpr int WN = BN / 2;      // wave col extent
  constexpr int NT = WN / 16;     // col MFMA tiles per wave
  const int tid  = threadIdx.x;
  const int lane = tid & 63, w = tid >> 6;
  const int quad = lane >> 4, l16 = lane & 15;
  const int wr = w >> 1, wc = w & 1;
  const int m0 = by * 128, n0 = bx * BN;

  f32x4 acc[4][NT] = {};

  constexpr int CHA = 128 * 8;    // A chunks (8 x 16B per 64-elem row)
  constexpr int CH  = CHA + BN * 8;
  constexpr int NCH = CH / 256;   // chunks per thread
  constexpr int NTK = K / 64;     // K-steps

  auto stage = [&](int kk, int buf) {
    bf16* Asb = As + buf * (128*64);
    bf16* Bsb = Bs + buf * (BN*64);
    #pragma unroll
    for (int t = 0; t < NCH; ++t) {
      int c0 = w*64 + t*256;      // wave-uniform LDS base chunk
      int ch = c0 + lane;
      if (c0 < CHA) {
        int r = ch >> 3, j = (ch & 7) ^ (r & 7);
        async_cp16(&A[(size_t)(m0 + r)*LD + kk + j*8], &Asb[(size_t)c0*8]);
      } else {
        int ch2 = ch - CHA, r = ch2 >> 3, j = (ch2 & 7) ^ (r & 7);
        async_cp16(&Bt[(size_t)(n0 + r)*LD + kk + j*8], &Bsb[(size_t)(c0 - CHA)*8]);
      }
    }
  };

  stage(0, 0);
  __syncthreads();   // vmcnt(0) drain + barrier

  #pragma unroll
  for (int t = 0; t < NTK; ++t) {
    const int buf = t & 1;
    if (t + 1 < NTK) stage((t + 1) * 64, buf ^ 1);

    const bf16* Asb = As + buf * (128*64);
    const bf16* Bsb = Bs + buf * (BN*64);

    #pragma unroll
    for (int kc = 0; kc < 2; ++kc) {
      bf16x8 bfr[NT];
      #pragma unroll
      for (int nt = 0; nt < NT; ++nt) {
        int rb = wc*WN + nt*16 + l16;
        int c  = (kc*4 + quad) ^ (rb & 7);
        bfr[nt] = *(const bf16x8*)&Bsb[rb*64 + c*8];
      }
      #pragma unroll
      for (int mt = 0; mt < 4; ++mt) {
        int ra = wr*64 + mt*16 + l16;
        int ca = (kc*4 + quad) ^ (ra & 7);
        bf16x8 af = *(const bf16x8*)&Asb[ra*64 + ca*8];
        #pragma unroll
        for (int nt = 0; nt < NT; ++nt)
          acc[mt][nt] = __builtin_amdgcn_mfma_f32_16x16x32_bf16(af, bfr[nt], acc[mt][nt], 0, 0, 0);
      }
    }
    if (t + 1 < NTK) __syncthreads();
  }

  #pragma unroll
  for (int mt = 0; mt < 4; ++mt) {
    #pragma unroll
    for (int nt = 0; nt < NT; ++nt) {
      int row = m0 + wr*64 + mt*16 + quad*4;
      int col = n0 + wc*WN + nt*16 + l16;
      if (GELU) {
        #pragma unroll
        for (int r = 0; r < 4; ++r) {
          float v = acc[mt][nt][r];
          float g = __shfl_xor(v, 1);            // even lane: v=a, g from odd
          if (!(lane & 1)) {
            float ge = 0.5f * g * (1.f + erff(g * 0.70710678118654752f));
            Cb[(size_t)(row + r)*(N >> 1) + (col >> 1)] = __float2bfloat16(v * ge);
          }
        }
      } else if (VOUT) {
        if (col < INNER) {                       // K half (wave-uniform branch)
          #pragma unroll
          for (int r = 0; r < 4; ++r)
            Cb[(size_t)(row + r)*INNER + col] = __float2bfloat16(acc[mt][nt][r]);
        } else {                                 // V half -> (b,h,dh,n) packed
          int c2 = col - INNER, hh = c2 >> 6, d = c2 & 63;
          int b = row >> 10, nn = row & 1023;
          union { ushort4 u4; bf16 h4[4]; } p;
          #pragma unroll
          for (int r = 0; r < 4; ++r) p.h4[r] = __float2bfloat16(acc[mt][nt][r]);
          *(ushort4*)&Vt[(((size_t)b*HEADS + hh)*DH + d)*NN + nn] = p.u4;
        }
      } else {
        #pragma unroll
        for (int r = 0; r < 4; ++r) {
          float v = acc[mt][nt][r];
          size_t idx = (size_t)(row + r) * N + col;
          if (Rf) v += Rf[idx];
          if (Cf) Cf[idx] = v;
          if (Cb) Cb[idx] = __float2bfloat16(v);
        }
      }
    }
  }
}

// Plain (non-split) GEMM with fused residual: x_out = Rf + A@Bt^T.
// R9: replaces splitk+redln for wo/ff2 — kills 25.2MB f32 partial write +
// 25.2MB re-read per pair, and doubles K-tiles/block (12 and 32) which is
// the good direction for this prologue-dominated small-K regime.
template<int BN, int K, int LD>
__global__ __launch_bounds__(256) void gemm_kernel(
    const bf16* __restrict__ A, const bf16* __restrict__ Bt,
    bf16* __restrict__ Cb, float* __restrict__ Cf, const float* __restrict__ Rf,
    int M, int N)
{
  __shared__ __align__(16) bf16 As[2*128*64];
  __shared__ __align__(16) bf16 Bs[2*BN*64];
  gemm_body<BN,false,false,K,LD>(A, Bt, Cb, Cf, Rf, nullptr, M, N,
                                 blockIdx.x, blockIdx.y, As, Bs);
}

// q = h @ wq (BN=64); kv = x @ wkv (BN=128, k compact + v transposed) fused
__global__ __launch_bounds__(256) void qkv_kernel(
    const bf16* __restrict__ h, const bf16* __restrict__ x16,
    const bf16* __restrict__ wqT, const bf16* __restrict__ wkvT,
    bf16* __restrict__ qb, bf16* __restrict__ kb, bf16* __restrict__ vt)
{
  __shared__ __align__(16) bf16 As[2*128*64];
  __shared__ __align__(16) bf16 Bs[2*128*64];
  if (blockIdx.z == 0)
    gemm_body<64,false,false,768,768>(h, wqT, qb, nullptr, nullptr, nullptr,
                                      ROWS, INNER, blockIdx.x, blockIdx.y, As, Bs);
  else
    gemm_body<128,false,true,768,768>(x16, wkvT, kb, nullptr, nullptr, vt,
                                      ROWS, 2*INNER, blockIdx.x, blockIdx.y, As, Bs);
}

// ---------------------------------------------------------------------------
// 256x256 8-wave GEMM + GELU for FF1 (M=N=4096, K=768). R6 2-PHASE form
// (measured 50.0us — the 8-phase counted-vmcnt variant was 53.5us even with
// 0 bank conflicts, R8). 2D-region XCD swizzle kept (FETCH 28->19MB).
// ---------------------------------------------------------------------------
__global__ __launch_bounds__(512) void gemm256_kernel(
    const bf16* __restrict__ A, const bf16* __restrict__ Bt,
    bf16* __restrict__ Cb, int M, int N)
{
  __shared__ __align__(16) bf16 As[2][256*64];
  __shared__ __align__(16) bf16 Bs[2][256*64];

  const int tid  = threadIdx.x;
  const int lane = tid & 63, wv = tid >> 6;
  const int quad = lane >> 4, l16 = lane & 15;
  const int wr = wv >> 2, wc = wv & 3;          // 2 x 4 wave grid

  // 2D-region XCD swizzle (bijective for the 16x16 grid)
  const int lin = blockIdx.y * gridDim.x + blockIdx.x;
  const int xcd = lin & 7, loc = lin >> 3;
  const int bxs = (xcd & 1) * 8 + (loc & 7);
  const int bys = (xcd >> 1) * 4 + (loc >> 3);
  const int m0 = bys * 256, n0 = bxs * 256;

  f32x4 acc[8][4] = {};

  auto stage = [&](int kk, int buf) {
    #pragma unroll
    for (int t = 0; t < 8; ++t) {
      int c0 = wv*64 + t*512;                   // wave-uniform base chunk
      int ch = c0 + lane;
      if (c0 < 2048) {
        int r = ch >> 3, j = (ch & 7) ^ (r & 7);
        async_cp16(&A[(size_t)(m0 + r)*768 + kk + j*8], &As[buf][(size_t)c0*8]);
      } else {
        int ch2 = ch - 2048, r = ch2 >> 3, j = (ch2 & 7) ^ (r & 7);
        async_cp16(&Bt[(size_t)(n0 + r)*768 + kk + j*8], &Bs[buf][(size_t)(c0 - 2048)*8]);
      }
    }
  };

  stage(0, 0);
  __syncthreads();

  #pragma unroll
  for (int t = 0; t < 12; ++t) {                // K = 768 = 12 x 64
    const int buf = t & 1;
    if (t + 1 < 12) stage((t + 1) * 64, buf ^ 1);

    const bf16* Asb = &As[buf][0];
    const bf16* Bsb = &Bs[buf][0];

    #pragma unroll
    for (int kc = 0; kc < 2; ++kc) {
      bf16x8 bfr[4];
      #pragma unroll
      for (int nt = 0; nt < 4; ++nt) {
        int rb = wc*64 + nt*16 + l16;
        int c  = (kc*4 + quad) ^ (rb & 7);
        bfr[nt] = *(const bf16x8*)&Bsb[rb*64 + c*8];
      }
      #pragma unroll
      for (int mt = 0; mt < 8; ++mt) {
        int ra = wr*128 + mt*16 + l16;
        int ca = (kc*4 + quad) ^ (ra & 7);
        bf16x8 af = *(const bf16x8*)&Asb[ra*64 + ca*8];
        #pragma unroll
        for (int nt = 0; nt < 4; ++nt)
          acc[mt][nt] = __builtin_amdgcn_mfma_f32_16x16x32_bf16(af, bfr[nt], acc[mt][nt], 0, 0, 0);
      }
    }
    if (t + 1 < 12) __syncthreads();
  }

  // GELU epilogue: cols interleave (a,g); even lane holds a, odd holds g
  #pragma unroll
  for (int mt = 0; mt < 8; ++mt) {
    #pragma unroll
    for (int nt = 0; nt < 4; ++nt) {
      int row = m0 + wr*128 + mt*16 + quad*4;
      int col = n0 + wc*64 + nt*16 + l16;
      #pragma unroll
      for (int r = 0; r < 4; ++r) {
        float v = acc[mt][nt][r];
        float g = __shfl_xor(v, 1);
        if (!(lane & 1)) {
          float ge = 0.5f * g * (1.f + erff(g * 0.70710678118654752f));
          Cb[(size_t)(row + r)*(N >> 1) + (col >> 1)] = __float2bfloat16(v * ge);
        }
      }
    }
  }
}

// ---------------------------------------------------------------------------
// LayerNorm (row = 768, f32 in, bf16 out). R9: now the ONLY normalization
// pass — residual adds live in the GEMM epilogues.
// ---------------------------------------------------------------------------
__global__ __launch_bounds__(256) void ln_kernel(
    const float* __restrict__ x, const float* __restrict__ g,
    const float* __restrict__ bta, bf16* __restrict__ out)
{
  const int row = blockIdx.x, tid = threadIdx.x;
  const size_t base = (size_t)row * DIM;
  float v[3];
  #pragma unroll
  for (int j = 0; j < 3; ++j) v[j] = x[base + tid + j*256];
  float s  = v[0] + v[1] + v[2];
  float ss = v[0]*v[0] + v[1]*v[1] + v[2]*v[2];
  #pragma unroll
  for (int off = 32; off; off >>= 1) { s += __shfl_xor(s, off); ss += __shfl_xor(ss, off); }
  __shared__ float red[8];
  int w = tid >> 6;
  if ((tid & 63) == 0) { red[w] = s; red[w + 4] = ss; }
  __syncthreads();
  s  = red[0] + red[1] + red[2] + red[3];
  ss = red[4] + red[5] + red[6] + red[7];
  float mean = s * (1.f/768.f);
  float var  = ss * (1.f/768.f) - mean*mean;
  float rstd = rsqrtf(fmaxf(var, 0.f) + 1e-5f);
  #pragma unroll
  for (int j = 0; j < 3; ++j) {
    int c = tid + j*256;
    float bv = bta ? bta[c] : 0.f;
    out[base + c] = __float2bfloat16((v[j] - mean) * rstd * g[c] + bv);
  }
}

// ---------------------------------------------------------------------------
// RoPE (2D, H=32) + L2-norm + per-dim scale; q gets ATTN_SCALE folded in.
// Pair-per-lane; block = 384 threads (12 heads x 32 pairs). -> (b,h,n,dh)
// ---------------------------------------------------------------------------
__global__ __launch_bounds__(384) void rope_kernel(
    const bf16* __restrict__ q, const bf16* __restrict__ kb,
    const float* __restrict__ qsc, const float* __restrict__ ksc,
    bf16* __restrict__ qh, bf16* __restrict__ kh)
{
  const int bn = blockIdx.x;
  const int b = bn >> 10, n = bn & 1023;
  const int tid = threadIdx.x;
  const int h = tid >> 5, pr = tid & 31, d0 = pr*2;
  const float xp = (float)(n & 31), yp = (float)(n >> 5);
  const int t = pr >> 1;
  const float freq = powf(10000.f, -(float)t / 16.f);
  const float ang = (pr & 1) ? yp * freq : xp * freq;
  float sn, cs;
  sincosf(ang, &sn, &cs);
  const float2 qs2 = *(const float2*)&qsc[d0];
  const float2 ks2 = *(const float2*)&ksc[d0];

  union { unsigned int u; bf16 h2[2]; } qa, ka, qo, ko;
  qa.u = *(const unsigned int*)&q [(size_t)bn*INNER + h*64 + d0];
  ka.u = *(const unsigned int*)&kb[(size_t)bn*INNER + h*64 + d0];
  float qre = __bfloat162float(qa.h2[0]), qim = __bfloat162float(qa.h2[1]);
  float kre = __bfloat162float(ka.h2[0]), kim = __bfloat162float(ka.h2[1]);
  float qr = qre*cs - qim*sn, qi = qre*sn + qim*cs;
  float kr = kre*cs - kim*sn, ki = kre*sn + kim*cs;
  float q2 = qr*qr + qi*qi, k2 = kr*kr + ki*ki;
  #pragma unroll
  for (int off = 1; off < 32; off <<= 1) { q2 += __shfl_xor(q2, off); k2 += __shfl_xor(k2, off); }
  float qinv = 8.f / fmaxf(sqrtf(q2), 1e-12f);   // ATTN_SCALE folded into q
  float kinv = 1.f / fmaxf(sqrtf(k2), 1e-12f);
  qo.h2[0] = __float2bfloat16(qr * qinv * qs2.x);
  qo.h2[1] = __float2bfloat16(qi * qinv * qs2.y);
  ko.h2[0] = __float2bfloat16(kr * kinv * ks2.x);
  ko.h2[1] = __float2bfloat16(ki * kinv * ks2.y);
  size_t oi = (((size_t)b*HEADS + h)*NN + n)*DH + d0;
  *(unsigned int*)&qh[oi] = qo.u;
  *(unsigned int*)&kh[oi] = ko.u;
}

// ---------------------------------------------------------------------------
// Flash attention, fixed softmax max (Cauchy-Schwarz bound; 8 folded into q).
// R6 structure (kept): async global_load_lds K/V staging, double-buffered
// 2-phase, XOR-swizzled unpadded LDS, 1 barrier/tile + same-wave Ps.
// ---------------------------------------------------------------------------
__global__ __launch_bounds__(256) void attn_kernel(
    const bf16* __restrict__ qh, const bf16* __restrict__ kh,
    const bf16* __restrict__ vt, const float* __restrict__ qsc,
    const float* __restrict__ ksc, bf16* __restrict__ ob)
{
  __shared__ __align__(16) bf16 Qs[64*64];
  __shared__ __align__(16) bf16 Ks[2][64*64];
  __shared__ __align__(16) bf16 Vs[2][64*64];
  __shared__ __align__(16) bf16 Ps[4][16*72];

  const int tid = threadIdx.x;
  const int lane = tid & 63, w = tid >> 6;
  const int quad = lane >> 4, l16 = lane & 15;
  const int qt = blockIdx.x, bh = blockIdx.y;
  const int b = bh / HEADS, h = bh % HEADS;
  const size_t base = (size_t)bh * NN * DH;

  float mq = fabsf(qsc[lane]), mk = fabsf(ksc[lane]);
  #pragma unroll
  for (int off = 1; off < 64; off <<= 1) {
    mq = fmaxf(mq, __shfl_xor(mq, off));
    mk = fmaxf(mk, __shfl_xor(mk, off));
  }
  const float Mb = 8.f * mq * mk;

  // stage Q once (512 chunks, 2/thread), pre-swizzled source -> linear dest
  #pragma unroll
  for (int t = 0; t < 2; ++t) {
    int c0 = w*64 + t*256, ch = c0 + lane;
    int r = ch >> 3, jl = (ch & 7) ^ (r & 7);
    async_cp16(&qh[base + (size_t)(qt*64 + r)*64 + jl*8], &Qs[(size_t)c0*8]);
  }

  // stage one K/V tile (1024 chunks, 4/thread) into buffer buf
  auto stage_kv = [&](int kt0, int buf) {
    #pragma unroll
    for (int t = 0; t < 4; ++t) {
      int c0 = w*64 + t*256, ch = c0 + lane;
      if (c0 < 512) {            // K: rows = n, cols = dh
        int r = ch >> 3, jl = (ch & 7) ^ (r & 7);
        async_cp16(&kh[base + (size_t)(kt0*64 + r)*64 + jl*8],
                   &Ks[buf][(size_t)c0*8]);
      } else {                   // V: rows = dh, cols = n (vt is (b,h,dh,n))
        int ch2 = ch - 512, r = ch2 >> 3, jl = (ch2 & 7) ^ (r & 7);
        async_cp16(&vt[base + (size_t)r*NN + kt0*64 + jl*8],
                   &Vs[buf][(size_t)(c0 - 512)*8]);
      }
    }
  };

  f32x4 o[4] = {};
  float pl[4] = {0.f, 0.f, 0.f, 0.f};

  stage_kv(0, 0);
  __syncthreads();               // drains Q + tile-0 loads

  for (int kt0 = 0; kt0 < NN/64; ++kt0) {
    const int buf = kt0 & 1;
    if (kt0 + 1 < NN/64) stage_kv(kt0 + 1, buf ^ 1);  // async, hides under MFMA

    f32x4 s[4] = {};
    bf16x8 aq[2];
    const int rq = w*16 + l16;
    #pragma unroll
    for (int kc = 0; kc < 2; ++kc)
      aq[kc] = *(const bf16x8*)&Qs[rq*64 + ((kc*4 + quad) ^ (rq & 7))*8];
    #pragma unroll
    for (int kt = 0; kt < 4; ++kt)
      #pragma unroll
      for (int kc = 0; kc < 2; ++kc) {
        int rb = kt*16 + l16;
        bf16x8 bk = *(const bf16x8*)&Ks[buf][rb*64 + ((kc*4 + quad) ^ (rb & 7))*8];
        s[kt] = __builtin_amdgcn_mfma_f32_16x16x32_bf16(aq[kc], bk, s[kt], 0, 0, 0);
      }

    #pragma unroll
    for (int r = 0; r < 4; ++r) {
      #pragma unroll
      for (int kt = 0; kt < 4; ++kt) {
        float pv = __expf(s[kt][r] - Mb);
        pl[r] += pv;
        Ps[w][(quad*4 + r)*72 + kt*16 + l16] = __float2bfloat16(pv);
      }
    }
    // no barrier: Ps[w] is produced and consumed by the same wave.

    #pragma unroll
    for (int kc = 0; kc < 2; ++kc) {
      bf16x8 ap = *(const bf16x8*)&Ps[w][l16*72 + kc*32 + quad*8];
      #pragma unroll
      for (int nt = 0; nt < 4; ++nt) {
        int rv = nt*16 + l16;
        bf16x8 bv = *(const bf16x8*)&Vs[buf][rv*64 + ((kc*4 + quad) ^ (rv & 7))*8];
        o[nt] = __builtin_amdgcn_mfma_f32_16x16x32_bf16(ap, bv, o[nt], 0, 0, 0);
      }
    }

    if (kt0 + 1 < NN/64) __syncthreads();
  }

  float l[4];
  #pragma unroll
  for (int r = 0; r < 4; ++r) {
    float rs = pl[r];
    #pragma unroll
    for (int off = 1; off < 16; off <<= 1) rs += __shfl_xor(rs, off);
    l[r] = rs;
  }

  #pragma unroll
  for (int nt = 0; nt < 4; ++nt)
    #pragma unroll
    for (int r = 0; r < 4; ++r) {
      int n = qt*64 + w*16 + quad*4 + r;
      int dcol = nt*16 + l16;
      ob[((size_t)(b*NN + n)*HEADS + h)*DH + dcol] = __float2bfloat16(o[nt][r] / l[r]);
    }
}

// ---------------------------------------------------------------------------
// f32 -> bf16 cast (vectorized x8)
// ---------------------------------------------------------------------------
__global__ __launch_bounds__(256) void cast_kernel(
    const float* __restrict__ x, bf16* __restrict__ o)
{
  size_t i = ((size_t)blockIdx.x*256 + threadIdx.x) * 8;
  float4 f0 = *(const float4*)(x + i);
  float4 f1 = *(const float4*)(x + i + 4);
  union { uint4 u; bf16 h[8]; } p;
  p.h[0] = __float2bfloat16(f0.x); p.h[1] = __float2bfloat16(f0.y);
  p.h[2] = __float2bfloat16(f0.z); p.h[3] = __float2bfloat16(f0.w);
  p.h[4] = __float2bfloat16(f1.x); p.h[5] = __float2bfloat16(f1.y);
  p.h[6] = __float2bfloat16(f1.z); p.h[7] = __float2bfloat16(f1.w);
  *(uint4*)(o + i) = p.u;
}

// ---------------------------------------------------------------------------
// Fused weight transpose: 5 weights f32 (RxC) -> bf16 (CxR), one dispatch.
// perm=1 (wff1): output rows interleave a/g columns.
// ---------------------------------------------------------------------------
struct TD { const float* src; bf16* dst; int R, C, base, perm; };
struct TDs5 { TD d[5]; };

__global__ __launch_bounds__(256) void wtrans_kernel(TDs5 a)
{
  const int blk = blockIdx.x;
  int di = 0;
  #pragma unroll
  for (int k = 1; k < 5; ++k) if (blk >= a.d[k].base) di = k;
  const TD d = a.d[di];
  const int local = blk - d.base;
  const int tilesX = d.C >> 5;
  const int by = local / tilesX, bx = local - by*tilesX;
  __shared__ float t[32][33];
  const int tx = threadIdx.x & 31, ty = threadIdx.x >> 5;
  const int c0 = bx*32, r0 = by*32;
  #pragma unroll
  for (int i = 0; i < 4; ++i)
    t[ty + i*8][tx] = d.src[(size_t)(r0 + ty + i*8)*d.C + c0 + tx];
  __syncthreads();
  const int half = d.C >> 1;
  #pragma unroll
  for (int i = 0; i < 4; ++i) {
    int c = c0 + ty + i*8;
    int rout = d.perm ? ((c < half) ? 2*c : 2*(c - half) + 1) : c;
    d.dst[(size_t)rout*d.R + r0 + tx] = __float2bfloat16(t[tx][ty + i*8]);
  }
}

// ---------------------------------------------------------------------------
extern "C" void kernel_launch(void* const* d_in, const int* in_sizes, int n_in,
                              void* d_out, int out_size, void* d_ws, size_t ws_size,
                              hipStream_t stream)
{
  const float* x_in       = (const float*)d_in[0];
  const float* attn_gamma = (const float*)d_in[1];
  const float* wq         = (const float*)d_in[2];
  const float* wkv        = (const float*)d_in[3];
  const float* q_scale    = (const float*)d_in[4];
  const float* k_scale    = (const float*)d_in[5];
  const float* wo         = (const float*)d_in[6];
  const float* ff_gamma   = (const float*)d_in[7];
  const float* ff_beta    = (const float*)d_in[8];
  const float* wff1       = (const float*)d_in[9];
  const float* wff2       = (const float*)d_in[10];
  float* outp = (float*)d_out;
  char* ws = (char*)d_ws;

  const size_t E = (size_t)ROWS * DIM;      // 3,145,728 elems
  float* xw32 = (float*)ws;                     // [0, 12.58M) f32 residual
  bf16*  xw16 = (bf16*)(ws + 12582912);         // bf16 shadow (kv input)
  bf16*  S_h  = (bf16*)(ws + 18874368);         // LN out / attn out
  char*  BIGb = ws + 25165824;                  // 37.75M scratch
  bf16*  WT   = (bf16*)(ws + 62914560);         // transposed weights
  bf16*  qbuf  = (bf16*)BIGb;                   // E elems
  bf16*  kbuf  = qbuf + E;                      // E
  bf16*  qhb   = qbuf + 2*E;                    // E
  bf16*  khb   = qbuf + 3*E;                    // E
  bf16*  vtb   = qbuf + 4*E;                    // E
  bf16*  glbuf = (bf16*)BIGb;                   // ROWS*FFI (q..vt dead by then)
  bf16*  wqT   = WT;                            // [768][768]
  bf16*  wkvT  = WT + 589824;                   // [1536][768]
  bf16*  woT   = WT + 1769472;                  // [768][768]
  bf16*  wff1T = WT + 2359296;                  // [4096][768] (interleaved a/g)
  bf16*  wff2T = WT + 5505024;                  // [768][2048]

  cast_kernel<<<1536, 256, 0, stream>>>(x_in, xw16);
  ln_kernel<<<ROWS, 256, 0, stream>>>(x_in, attn_gamma, nullptr, S_h);

  for (int i = 0; i < NDEPTH; ++i) {
    const float* xsrc = (i == 0) ? x_in : xw32;

    TDs5 td;
    td.d[0] = { wq   + (size_t)i*589824,  wqT,   768,  768,    0, 0 };
    td.d[1] = { wkv  + (size_t)i*1179648, wkvT,  768, 1536,  576, 0 };
    td.d[2] = { wo   + (size_t)i*589824,  woT,   768,  768, 1728, 0 };
    td.d[3] = { wff1 + (size_t)i*3145728, wff1T, 768, 4096, 2304, 1 };
    td.d[4] = { wff2 + (size_t)i*1572864, wff2T, 2048, 768, 5376, 0 };
    wtrans_kernel<<<6912, 256, 0, stream>>>(td);

    // q = LN_attn(x) @ wq ; k,v = x @ wkv (k compact, v transposed in-epilogue)
    qkv_kernel<<<dim3(12,32,2), 256, 0, stream>>>(S_h, xw16, wqT, wkvT, qbuf, kbuf, vtb);
    // rope(q,k) + l2norm + scale (8 folded into q)
    rope_kernel<<<ROWS, 384, 0, stream>>>(qbuf, kbuf, q_scale + i*DH, k_scale + i*DH, qhb, khb);
    attn_kernel<<<dim3(16,48), 256, 0, stream>>>(qhb, khb, vtb,
                                                 q_scale + i*DH, k_scale + i*DH, S_h);
    // x = x + o @ wo — residual FUSED in epilogue (no split-K, no partials)
    gemm_kernel<64,768,768><<<dim3(12,32), 256, 0, stream>>>(S_h, woT, nullptr, xw32, xsrc, ROWS, DIM);
    // ff-LN
    ln_kernel<<<ROWS, 256, 0, stream>>>(xw32, ff_gamma + i*DIM, ff_beta + i*DIM, S_h);
    // gl = a*gelu(g) fused in FF1 epilogue (256^2 2-phase kernel)
    gemm256_kernel<<<dim3(16,16), 512, 0, stream>>>(S_h, wff1T, glbuf, ROWS, 2*FFI);
    // x = x + gl @ wff2 — residual fused; bf16 shadow written for next layer
    if (i < NDEPTH-1) {
      gemm_kernel<64,2048,2048><<<dim3(12,32), 256, 0, stream>>>(glbuf, wff2T, xw16, xw32, xw32, ROWS, DIM);
      // next attn-LN
      ln_kernel<<<ROWS, 256, 0, stream>>>(xw32, attn_gamma + (i+1)*DIM, nullptr, S_h);
    } else {
      gemm_kernel<64,2048,2048><<<dim3(12,32), 256, 0, stream>>>(glbuf, wff2T, nullptr, outp, xw32, ROWS, DIM);
    }
  }
}

// Round 10
// 906.981 us; speedup vs baseline: 1.4675x; 1.4675x over previous
//
#include <hip/hip_runtime.h>
#include <hip/hip_bf16.h>
#include <math.h>

typedef __hip_bfloat16 bf16;
typedef __bf16 bf16x8 __attribute__((ext_vector_type(8)));
typedef float f32x4 __attribute__((ext_vector_type(4)));

#define NDEPTH 4
#define DIM 768
#define HEADS 12
#define DH 64
#define INNER 768
#define FFI 2048
#define BB 4
#define NN 1024
#define ROWS (BB*NN)   // 4096

__device__ __forceinline__ void async_cp16(const bf16* g, bf16* l) {
  __builtin_amdgcn_global_load_lds(
      (const __attribute__((address_space(1))) unsigned int*)g,
      (__attribute__((address_space(3))) unsigned int*)l, 16, 0, 0);
}

// ---------------------------------------------------------------------------
// bf16 MFMA GEMM body (R1 config — measured best for the N<=1536 GEMMs).
// C[MxN] = A[MxK] @ Bt[NxK]^T. 128xBN tile, BK=64, 4 waves, XOR-swizzled LDS
// (0 bank conflicts measured). 2-phase double-buffered pipeline: stage next
// K-tile before computing current; one __syncthreads per step.
// GEMM-plateau history: depth-2/3-buffer (R2), 1D XCD swizzle (R3), BK=32
// (R4), 256^2 2ph (R5 neutral), 8-phase counted-vmcnt (R7/R8 null after
// conflict fix), fused non-split K=2048 (R9: -46% ANOMALY, unexplained —
// identical gemm256 code stalled 2.2x more cycles; reverted). ~500 TF is
// this small-K regime's measured plateau across 6 structural variants.
// ---------------------------------------------------------------------------
template<int BN, bool GELU, bool VOUT, int K, int LD>
__device__ __forceinline__ void gemm_body(
    const bf16* __restrict__ A, const bf16* __restrict__ Bt,
    bf16* __restrict__ Cb, float* __restrict__ Cf, const float* __restrict__ Rf,
    bf16* __restrict__ Vt, int M, int N, int bx, int by, bf16* As, bf16* Bs)
{
  constexpr int WN = BN / 2;      // wave col extent
  constexpr int NT = WN / 16;     // col MFMA tiles per wave
  const int tid  = threadIdx.x;
  const int lane = tid & 63, w = tid >> 6;
  const int quad = lane >> 4, l16 = lane & 15;
  const int wr = w >> 1, wc = w & 1;
  const int m0 = by * 128, n0 = bx * BN;

  f32x4 acc[4][NT] = {};

  constexpr int CHA = 128 * 8;    // A chunks (8 x 16B per 64-elem row)
  constexpr int CH  = CHA + BN * 8;
  constexpr int NCH = CH / 256;   // chunks per thread
  constexpr int NTK = K / 64;     // K-steps

  auto stage = [&](int kk, int buf) {
    bf16* Asb = As + buf * (128*64);
    bf16* Bsb = Bs + buf * (BN*64);
    #pragma unroll
    for (int t = 0; t < NCH; ++t) {
      int c0 = w*64 + t*256;      // wave-uniform LDS base chunk
      int ch = c0 + lane;
      if (c0 < CHA) {
        int r = ch >> 3, j = (ch & 7) ^ (r & 7);
        async_cp16(&A[(size_t)(m0 + r)*LD + kk + j*8], &Asb[(size_t)c0*8]);
      } else {
        int ch2 = ch - CHA, r = ch2 >> 3, j = (ch2 & 7) ^ (r & 7);
        async_cp16(&Bt[(size_t)(n0 + r)*LD + kk + j*8], &Bsb[(size_t)(c0 - CHA)*8]);
      }
    }
  };

  stage(0, 0);
  __syncthreads();   // vmcnt(0) drain + barrier

  #pragma unroll
  for (int t = 0; t < NTK; ++t) {
    const int buf = t & 1;
    if (t + 1 < NTK) stage((t + 1) * 64, buf ^ 1);

    const bf16* Asb = As + buf * (128*64);
    const bf16* Bsb = Bs + buf * (BN*64);

    #pragma unroll
    for (int kc = 0; kc < 2; ++kc) {
      bf16x8 bfr[NT];
      #pragma unroll
      for (int nt = 0; nt < NT; ++nt) {
        int rb = wc*WN + nt*16 + l16;
        int c  = (kc*4 + quad) ^ (rb & 7);
        bfr[nt] = *(const bf16x8*)&Bsb[rb*64 + c*8];
      }
      #pragma unroll
      for (int mt = 0; mt < 4; ++mt) {
        int ra = wr*64 + mt*16 + l16;
        int ca = (kc*4 + quad) ^ (ra & 7);
        bf16x8 af = *(const bf16x8*)&Asb[ra*64 + ca*8];
        #pragma unroll
        for (int nt = 0; nt < NT; ++nt)
          acc[mt][nt] = __builtin_amdgcn_mfma_f32_16x16x32_bf16(af, bfr[nt], acc[mt][nt], 0, 0, 0);
      }
    }
    if (t + 1 < NTK) __syncthreads();
  }

  #pragma unroll
  for (int mt = 0; mt < 4; ++mt) {
    #pragma unroll
    for (int nt = 0; nt < NT; ++nt) {
      int row = m0 + wr*64 + mt*16 + quad*4;
      int col = n0 + wc*WN + nt*16 + l16;
      if (GELU) {
        #pragma unroll
        for (int r = 0; r < 4; ++r) {
          float v = acc[mt][nt][r];
          float g = __shfl_xor(v, 1);            // even lane: v=a, g from odd
          if (!(lane & 1)) {
            float ge = 0.5f * g * (1.f + erff(g * 0.70710678118654752f));
            Cb[(size_t)(row + r)*(N >> 1) + (col >> 1)] = __float2bfloat16(v * ge);
          }
        }
      } else if (VOUT) {
        if (col < INNER) {                       // K half (wave-uniform branch)
          #pragma unroll
          for (int r = 0; r < 4; ++r)
            Cb[(size_t)(row + r)*INNER + col] = __float2bfloat16(acc[mt][nt][r]);
        } else {                                 // V half -> (b,h,dh,n) packed
          int c2 = col - INNER, hh = c2 >> 6, d = c2 & 63;
          int b = row >> 10, nn = row & 1023;
          union { ushort4 u4; bf16 h4[4]; } p;
          #pragma unroll
          for (int r = 0; r < 4; ++r) p.h4[r] = __float2bfloat16(acc[mt][nt][r]);
          *(ushort4*)&Vt[(((size_t)b*HEADS + hh)*DH + d)*NN + nn] = p.u4;
        }
      } else {
        #pragma unroll
        for (int r = 0; r < 4; ++r) {
          float v = acc[mt][nt][r];
          size_t idx = (size_t)(row + r) * N + col;
          if (Rf) v += Rf[idx];
          if (Cf) Cf[idx] = v;
          if (Cb) Cb[idx] = __float2bfloat16(v);
        }
      }
    }
  }
}

// Split-K=2: z selects K-half; partials to P[z*M*N]
template<int BN, int KH, int LD>
__global__ __launch_bounds__(256) void gemm_splitk_kernel(
    const bf16* __restrict__ A, const bf16* __restrict__ Bt,
    float* __restrict__ P, int M, int N)
{
  __shared__ __align__(16) bf16 As[2*128*64];
  __shared__ __align__(16) bf16 Bs[2*BN*64];
  const int z = blockIdx.z;
  gemm_body<BN,false,false,KH,LD>(A + (size_t)z*KH, Bt + (size_t)z*KH, nullptr,
                                  P + (size_t)z*M*N, nullptr, nullptr,
                                  M, N, blockIdx.x, blockIdx.y, As, Bs);
}

// q = h @ wq (BN=64); kv = x @ wkv (BN=128, k compact + v transposed) fused
__global__ __launch_bounds__(256) void qkv_kernel(
    const bf16* __restrict__ h, const bf16* __restrict__ x16,
    const bf16* __restrict__ wqT, const bf16* __restrict__ wkvT,
    bf16* __restrict__ qb, bf16* __restrict__ kb, bf16* __restrict__ vt)
{
  __shared__ __align__(16) bf16 As[2*128*64];
  __shared__ __align__(16) bf16 Bs[2*128*64];
  if (blockIdx.z == 0)
    gemm_body<64,false,false,768,768>(h, wqT, qb, nullptr, nullptr, nullptr,
                                      ROWS, INNER, blockIdx.x, blockIdx.y, As, Bs);
  else
    gemm_body<128,false,true,768,768>(x16, wkvT, kb, nullptr, nullptr, vt,
                                      ROWS, 2*INNER, blockIdx.x, blockIdx.y, As, Bs);
}

// ---------------------------------------------------------------------------
// 256x256 8-wave GEMM + GELU for FF1 (M=N=4096, K=768). R6 2-PHASE form
// (measured 50.0us — best). 2D-region XCD swizzle kept (FETCH 28->19MB).
// ---------------------------------------------------------------------------
__global__ __launch_bounds__(512) void gemm256_kernel(
    const bf16* __restrict__ A, const bf16* __restrict__ Bt,
    bf16* __restrict__ Cb, int M, int N)
{
  __shared__ __align__(16) bf16 As[2][256*64];
  __shared__ __align__(16) bf16 Bs[2][256*64];

  const int tid  = threadIdx.x;
  const int lane = tid & 63, wv = tid >> 6;
  const int quad = lane >> 4, l16 = lane & 15;
  const int wr = wv >> 2, wc = wv & 3;          // 2 x 4 wave grid

  // 2D-region XCD swizzle (bijective for the 16x16 grid)
  const int lin = blockIdx.y * gridDim.x + blockIdx.x;
  const int xcd = lin & 7, loc = lin >> 3;
  const int bxs = (xcd & 1) * 8 + (loc & 7);
  const int bys = (xcd >> 1) * 4 + (loc >> 3);
  const int m0 = bys * 256, n0 = bxs * 256;

  f32x4 acc[8][4] = {};

  auto stage = [&](int kk, int buf) {
    #pragma unroll
    for (int t = 0; t < 8; ++t) {
      int c0 = wv*64 + t*512;                   // wave-uniform base chunk
      int ch = c0 + lane;
      if (c0 < 2048) {
        int r = ch >> 3, j = (ch & 7) ^ (r & 7);
        async_cp16(&A[(size_t)(m0 + r)*768 + kk + j*8], &As[buf][(size_t)c0*8]);
      } else {
        int ch2 = ch - 2048, r = ch2 >> 3, j = (ch2 & 7) ^ (r & 7);
        async_cp16(&Bt[(size_t)(n0 + r)*768 + kk + j*8], &Bs[buf][(size_t)(c0 - 2048)*8]);
      }
    }
  };

  stage(0, 0);
  __syncthreads();

  #pragma unroll
  for (int t = 0; t < 12; ++t) {                // K = 768 = 12 x 64
    const int buf = t & 1;
    if (t + 1 < 12) stage((t + 1) * 64, buf ^ 1);

    const bf16* Asb = &As[buf][0];
    const bf16* Bsb = &Bs[buf][0];

    #pragma unroll
    for (int kc = 0; kc < 2; ++kc) {
      bf16x8 bfr[4];
      #pragma unroll
      for (int nt = 0; nt < 4; ++nt) {
        int rb = wc*64 + nt*16 + l16;
        int c  = (kc*4 + quad) ^ (rb & 7);
        bfr[nt] = *(const bf16x8*)&Bsb[rb*64 + c*8];
      }
      #pragma unroll
      for (int mt = 0; mt < 8; ++mt) {
        int ra = wr*128 + mt*16 + l16;
        int ca = (kc*4 + quad) ^ (ra & 7);
        bf16x8 af = *(const bf16x8*)&Asb[ra*64 + ca*8];
        #pragma unroll
        for (int nt = 0; nt < 4; ++nt)
          acc[mt][nt] = __builtin_amdgcn_mfma_f32_16x16x32_bf16(af, bfr[nt], acc[mt][nt], 0, 0, 0);
      }
    }
    if (t + 1 < 12) __syncthreads();
  }

  // GELU epilogue: cols interleave (a,g); even lane holds a, odd holds g
  #pragma unroll
  for (int mt = 0; mt < 8; ++mt) {
    #pragma unroll
    for (int nt = 0; nt < 4; ++nt) {
      int row = m0 + wr*128 + mt*16 + quad*4;
      int col = n0 + wc*64 + nt*16 + l16;
      #pragma unroll
      for (int r = 0; r < 4; ++r) {
        float v = acc[mt][nt][r];
        float g = __shfl_xor(v, 1);
        if (!(lane & 1)) {
          float ge = 0.5f * g * (1.f + erff(g * 0.70710678118654752f));
          Cb[(size_t)(row + r)*(N >> 1) + (col >> 1)] = __float2bfloat16(v * ge);
        }
      }
    }
  }
}

// ---------------------------------------------------------------------------
// LayerNorm (row = 768, f32 in, bf16 out) — used once for layer-0 attn-LN
// ---------------------------------------------------------------------------
__global__ __launch_bounds__(256) void ln_kernel(
    const float* __restrict__ x, const float* __restrict__ g,
    const float* __restrict__ bta, bf16* __restrict__ out)
{
  const int row = blockIdx.x, tid = threadIdx.x;
  const size_t base = (size_t)row * DIM;
  float v[3];
  #pragma unroll
  for (int j = 0; j < 3; ++j) v[j] = x[base + tid + j*256];
  float s  = v[0] + v[1] + v[2];
  float ss = v[0]*v[0] + v[1]*v[1] + v[2]*v[2];
  #pragma unroll
  for (int off = 32; off; off >>= 1) { s += __shfl_xor(s, off); ss += __shfl_xor(ss, off); }
  __shared__ float red[8];
  int w = tid >> 6;
  if ((tid & 63) == 0) { red[w] = s; red[w + 4] = ss; }
  __syncthreads();
  s  = red[0] + red[1] + red[2] + red[3];
  ss = red[4] + red[5] + red[6] + red[7];
  float mean = s * (1.f/768.f);
  float var  = ss * (1.f/768.f) - mean*mean;
  float rstd = rsqrtf(fmaxf(var, 0.f) + 1e-5f);
  #pragma unroll
  for (int j = 0; j < 3; ++j) {
    int c = tid + j*256;
    float bv = bta ? bta[c] : 0.f;
    out[base + c] = __float2bfloat16((v[j] - mean) * rstd * g[c] + bv);
  }
}

// ---------------------------------------------------------------------------
// Split-K reduce + residual + optional LN (fused). Row = 768.
// ---------------------------------------------------------------------------
__global__ __launch_bounds__(256) void redln_kernel(
    const float* __restrict__ P0, const float* __restrict__ P1,
    const float* __restrict__ res,
    float* __restrict__ xo32, bf16* __restrict__ xo16, float* __restrict__ outf,
    const float* __restrict__ g, const float* __restrict__ bta,
    bf16* __restrict__ lnout)
{
  const int row = blockIdx.x, tid = threadIdx.x;
  const size_t base = (size_t)row * DIM;
  float v[3];
  #pragma unroll
  for (int j = 0; j < 3; ++j) {
    size_t idx = base + tid + j*256;
    v[j] = res[idx] + P0[idx] + P1[idx];
    if (xo32) xo32[idx] = v[j];
    if (xo16) xo16[idx] = __float2bfloat16(v[j]);
    if (outf) outf[idx] = v[j];
  }
  if (!g) return;
  float s  = v[0] + v[1] + v[2];
  float ss = v[0]*v[0] + v[1]*v[1] + v[2]*v[2];
  #pragma unroll
  for (int off = 32; off; off >>= 1) { s += __shfl_xor(s, off); ss += __shfl_xor(ss, off); }
  __shared__ float red[8];
  int w = tid >> 6;
  if ((tid & 63) == 0) { red[w] = s; red[w + 4] = ss; }
  __syncthreads();
  s  = red[0] + red[1] + red[2] + red[3];
  ss = red[4] + red[5] + red[6] + red[7];
  float mean = s * (1.f/768.f);
  float var  = ss * (1.f/768.f) - mean*mean;
  float rstd = rsqrtf(fmaxf(var, 0.f) + 1e-5f);
  #pragma unroll
  for (int j = 0; j < 3; ++j) {
    int c = tid + j*256;
    float bv = bta ? bta[c] : 0.f;
    lnout[base + c] = __float2bfloat16((v[j] - mean) * rstd * g[c] + bv);
  }
}

// ---------------------------------------------------------------------------
// RoPE (2D, H=32) + L2-norm + per-dim scale; q gets ATTN_SCALE folded in.
// Pair-per-lane; block = 384 threads (12 heads x 32 pairs). -> (b,h,n,dh)
// ---------------------------------------------------------------------------
__global__ __launch_bounds__(384) void rope_kernel(
    const bf16* __restrict__ q, const bf16* __restrict__ kb,
    const float* __restrict__ qsc, const float* __restrict__ ksc,
    bf16* __restrict__ qh, bf16* __restrict__ kh)
{
  const int bn = blockIdx.x;
  const int b = bn >> 10, n = bn & 1023;
  const int tid = threadIdx.x;
  const int h = tid >> 5, pr = tid & 31, d0 = pr*2;
  const float xp = (float)(n & 31), yp = (float)(n >> 5);
  const int t = pr >> 1;
  const float freq = powf(10000.f, -(float)t / 16.f);
  const float ang = (pr & 1) ? yp * freq : xp * freq;
  float sn, cs;
  sincosf(ang, &sn, &cs);
  const float2 qs2 = *(const float2*)&qsc[d0];
  const float2 ks2 = *(const float2*)&ksc[d0];

  union { unsigned int u; bf16 h2[2]; } qa, ka, qo, ko;
  qa.u = *(const unsigned int*)&q [(size_t)bn*INNER + h*64 + d0];
  ka.u = *(const unsigned int*)&kb[(size_t)bn*INNER + h*64 + d0];
  float qre = __bfloat162float(qa.h2[0]), qim = __bfloat162float(qa.h2[1]);
  float kre = __bfloat162float(ka.h2[0]), kim = __bfloat162float(ka.h2[1]);
  float qr = qre*cs - qim*sn, qi = qre*sn + qim*cs;
  float kr = kre*cs - kim*sn, ki = kre*sn + kim*cs;
  float q2 = qr*qr + qi*qi, k2 = kr*kr + ki*ki;
  #pragma unroll
  for (int off = 1; off < 32; off <<= 1) { q2 += __shfl_xor(q2, off); k2 += __shfl_xor(k2, off); }
  float qinv = 8.f / fmaxf(sqrtf(q2), 1e-12f);   // ATTN_SCALE folded into q
  float kinv = 1.f / fmaxf(sqrtf(k2), 1e-12f);
  qo.h2[0] = __float2bfloat16(qr * qinv * qs2.x);
  qo.h2[1] = __float2bfloat16(qi * qinv * qs2.y);
  ko.h2[0] = __float2bfloat16(kr * kinv * ks2.x);
  ko.h2[1] = __float2bfloat16(ki * kinv * ks2.y);
  size_t oi = (((size_t)b*HEADS + h)*NN + n)*DH + d0;
  *(unsigned int*)&qh[oi] = qo.u;
  *(unsigned int*)&kh[oi] = ko.u;
}

// ---------------------------------------------------------------------------
// Flash attention, fixed softmax max (Cauchy-Schwarz bound; 8 folded into q).
// R6 structure + R10: T5 s_setprio(1) around the QK and PV MFMA clusters.
// Mechanism (m191): 3 independent blocks/CU at uncorrelated phases — the
// scheduler can favor MFMA-entering waves over load-issuing waves of OTHER
// blocks. (m190's null was barrier-locked single-block GEMM; attn here has
// cross-block phase diversity.)
// ---------------------------------------------------------------------------
__global__ __launch_bounds__(256) void attn_kernel(
    const bf16* __restrict__ qh, const bf16* __restrict__ kh,
    const bf16* __restrict__ vt, const float* __restrict__ qsc,
    const float* __restrict__ ksc, bf16* __restrict__ ob)
{
  __shared__ __align__(16) bf16 Qs[64*64];
  __shared__ __align__(16) bf16 Ks[2][64*64];
  __shared__ __align__(16) bf16 Vs[2][64*64];
  __shared__ __align__(16) bf16 Ps[4][16*72];

  const int tid = threadIdx.x;
  const int lane = tid & 63, w = tid >> 6;
  const int quad = lane >> 4, l16 = lane & 15;
  const int qt = blockIdx.x, bh = blockIdx.y;
  const int b = bh / HEADS, h = bh % HEADS;
  const size_t base = (size_t)bh * NN * DH;

  float mq = fabsf(qsc[lane]), mk = fabsf(ksc[lane]);
  #pragma unroll
  for (int off = 1; off < 64; off <<= 1) {
    mq = fmaxf(mq, __shfl_xor(mq, off));
    mk = fmaxf(mk, __shfl_xor(mk, off));
  }
  const float Mb = 8.f * mq * mk;

  // stage Q once (512 chunks, 2/thread), pre-swizzled source -> linear dest
  #pragma unroll
  for (int t = 0; t < 2; ++t) {
    int c0 = w*64 + t*256, ch = c0 + lane;
    int r = ch >> 3, jl = (ch & 7) ^ (r & 7);
    async_cp16(&qh[base + (size_t)(qt*64 + r)*64 + jl*8], &Qs[(size_t)c0*8]);
  }

  // stage one K/V tile (1024 chunks, 4/thread) into buffer buf
  auto stage_kv = [&](int kt0, int buf) {
    #pragma unroll
    for (int t = 0; t < 4; ++t) {
      int c0 = w*64 + t*256, ch = c0 + lane;
      if (c0 < 512) {            // K: rows = n, cols = dh
        int r = ch >> 3, jl = (ch & 7) ^ (r & 7);
        async_cp16(&kh[base + (size_t)(kt0*64 + r)*64 + jl*8],
                   &Ks[buf][(size_t)c0*8]);
      } else {                   // V: rows = dh, cols = n (vt is (b,h,dh,n))
        int ch2 = ch - 512, r = ch2 >> 3, jl = (ch2 & 7) ^ (r & 7);
        async_cp16(&vt[base + (size_t)r*NN + kt0*64 + jl*8],
                   &Vs[buf][(size_t)(c0 - 512)*8]);
      }
    }
  };

  f32x4 o[4] = {};
  float pl[4] = {0.f, 0.f, 0.f, 0.f};

  stage_kv(0, 0);
  __syncthreads();               // drains Q + tile-0 loads

  for (int kt0 = 0; kt0 < NN/64; ++kt0) {
    const int buf = kt0 & 1;
    if (kt0 + 1 < NN/64) stage_kv(kt0 + 1, buf ^ 1);  // async, hides under MFMA

    f32x4 s[4] = {};
    bf16x8 aq[2];
    const int rq = w*16 + l16;
    #pragma unroll
    for (int kc = 0; kc < 2; ++kc)
      aq[kc] = *(const bf16x8*)&Qs[rq*64 + ((kc*4 + quad) ^ (rq & 7))*8];
    __builtin_amdgcn_s_setprio(1);
    #pragma unroll
    for (int kt = 0; kt < 4; ++kt)
      #pragma unroll
      for (int kc = 0; kc < 2; ++kc) {
        int rb = kt*16 + l16;
        bf16x8 bk = *(const bf16x8*)&Ks[buf][rb*64 + ((kc*4 + quad) ^ (rb & 7))*8];
        s[kt] = __builtin_amdgcn_mfma_f32_16x16x32_bf16(aq[kc], bk, s[kt], 0, 0, 0);
      }
    __builtin_amdgcn_s_setprio(0);

    #pragma unroll
    for (int r = 0; r < 4; ++r) {
      #pragma unroll
      for (int kt = 0; kt < 4; ++kt) {
        float pv = __expf(s[kt][r] - Mb);
        pl[r] += pv;
        Ps[w][(quad*4 + r)*72 + kt*16 + l16] = __float2bfloat16(pv);
      }
    }
    // no barrier: Ps[w] is produced and consumed by the same wave.

    __builtin_amdgcn_s_setprio(1);
    #pragma unroll
    for (int kc = 0; kc < 2; ++kc) {
      bf16x8 ap = *(const bf16x8*)&Ps[w][l16*72 + kc*32 + quad*8];
      #pragma unroll
      for (int nt = 0; nt < 4; ++nt) {
        int rv = nt*16 + l16;
        bf16x8 bv = *(const bf16x8*)&Vs[buf][rv*64 + ((kc*4 + quad) ^ (rv & 7))*8];
        o[nt] = __builtin_amdgcn_mfma_f32_16x16x32_bf16(ap, bv, o[nt], 0, 0, 0);
      }
    }
    __builtin_amdgcn_s_setprio(0);

    if (kt0 + 1 < NN/64) __syncthreads();
  }

  float l[4];
  #pragma unroll
  for (int r = 0; r < 4; ++r) {
    float rs = pl[r];
    #pragma unroll
    for (int off = 1; off < 16; off <<= 1) rs += __shfl_xor(rs, off);
    l[r] = rs;
  }

  #pragma unroll
  for (int nt = 0; nt < 4; ++nt)
    #pragma unroll
    for (int r = 0; r < 4; ++r) {
      int n = qt*64 + w*16 + quad*4 + r;
      int dcol = nt*16 + l16;
      ob[((size_t)(b*NN + n)*HEADS + h)*DH + dcol] = __float2bfloat16(o[nt][r] / l[r]);
    }
}

// ---------------------------------------------------------------------------
// f32 -> bf16 cast (vectorized x8)
// ---------------------------------------------------------------------------
__global__ __launch_bounds__(256) void cast_kernel(
    const float* __restrict__ x, bf16* __restrict__ o)
{
  size_t i = ((size_t)blockIdx.x*256 + threadIdx.x) * 8;
  float4 f0 = *(const float4*)(x + i);
  float4 f1 = *(const float4*)(x + i + 4);
  union { uint4 u; bf16 h[8]; } p;
  p.h[0] = __float2bfloat16(f0.x); p.h[1] = __float2bfloat16(f0.y);
  p.h[2] = __float2bfloat16(f0.z); p.h[3] = __float2bfloat16(f0.w);
  p.h[4] = __float2bfloat16(f1.x); p.h[5] = __float2bfloat16(f1.y);
  p.h[6] = __float2bfloat16(f1.z); p.h[7] = __float2bfloat16(f1.w);
  *(uint4*)(o + i) = p.u;
}

// ---------------------------------------------------------------------------
// Fused weight transpose: 5 weights f32 (RxC) -> bf16 (CxR), one dispatch.
// perm=1 (wff1): output rows interleave a/g columns.
// ---------------------------------------------------------------------------
struct TD { const float* src; bf16* dst; int R, C, base, perm; };
struct TDs5 { TD d[5]; };

__global__ __launch_bounds__(256) void wtrans_kernel(TDs5 a)
{
  const int blk = blockIdx.x;
  int di = 0;
  #pragma unroll
  for (int k = 1; k < 5; ++k) if (blk >= a.d[k].base) di = k;
  const TD d = a.d[di];
  const int local = blk - d.base;
  const int tilesX = d.C >> 5;
  const int by = local / tilesX, bx = local - by*tilesX;
  __shared__ float t[32][33];
  const int tx = threadIdx.x & 31, ty = threadIdx.x >> 5;
  const int c0 = bx*32, r0 = by*32;
  #pragma unroll
  for (int i = 0; i < 4; ++i)
    t[ty + i*8][tx] = d.src[(size_t)(r0 + ty + i*8)*d.C + c0 + tx];
  __syncthreads();
  const int half = d.C >> 1;
  #pragma unroll
  for (int i = 0; i < 4; ++i) {
    int c = c0 + ty + i*8;
    int rout = d.perm ? ((c < half) ? 2*c : 2*(c - half) + 1) : c;
    d.dst[(size_t)rout*d.R + r0 + tx] = __float2bfloat16(t[tx][ty + i*8]);
  }
}

// ---------------------------------------------------------------------------
extern "C" void kernel_launch(void* const* d_in, const int* in_sizes, int n_in,
                              void* d_out, int out_size, void* d_ws, size_t ws_size,
                              hipStream_t stream)
{
  const float* x_in       = (const float*)d_in[0];
  const float* attn_gamma = (const float*)d_in[1];
  const float* wq         = (const float*)d_in[2];
  const float* wkv        = (const float*)d_in[3];
  const float* q_scale    = (const float*)d_in[4];
  const float* k_scale    = (const float*)d_in[5];
  const float* wo         = (const float*)d_in[6];
  const float* ff_gamma   = (const float*)d_in[7];
  const float* ff_beta    = (const float*)d_in[8];
  const float* wff1       = (const float*)d_in[9];
  const float* wff2       = (const float*)d_in[10];
  float* outp = (float*)d_out;
  char* ws = (char*)d_ws;

  const size_t E = (size_t)ROWS * DIM;      // 3,145,728 elems
  float* xw32 = (float*)ws;                     // [0, 12.58M) f32 residual
  bf16*  xw16 = (bf16*)(ws + 12582912);         // bf16 shadow (kv input)
  bf16*  S_h  = (bf16*)(ws + 18874368);         // LN out / attn out
  char*  BIGb = ws + 25165824;                  // 37.75M scratch
  bf16*  WT   = (bf16*)(ws + 62914560);         // transposed weights
  bf16*  qbuf  = (bf16*)BIGb;                   // E elems
  bf16*  kbuf  = qbuf + E;                      // E
  bf16*  qhb   = qbuf + 2*E;                    // E
  bf16*  khb   = qbuf + 3*E;                    // E
  bf16*  vtb   = qbuf + 4*E;                    // E
  bf16*  glbuf = (bf16*)BIGb;                   // ROWS*FFI (q..vt dead by then)
  float* wP    = (float*)BIGb;                  // wo partials 2E f32
  float* fP    = (float*)(BIGb + 16777216);     // ff2 partials 2E f32 (tail
                                                //   spills into dead wqT..woT,
                                                //   rebuilt next layer)
  bf16*  wqT   = WT;                            // [768][768]
  bf16*  wkvT  = WT + 589824;                   // [1536][768]
  bf16*  woT   = WT + 1769472;                  // [768][768]
  bf16*  wff1T = WT + 2359296;                  // [4096][768] (interleaved a/g)
  bf16*  wff2T = WT + 5505024;                  // [768][2048]

  cast_kernel<<<1536, 256, 0, stream>>>(x_in, xw16);
  ln_kernel<<<ROWS, 256, 0, stream>>>(x_in, attn_gamma, nullptr, S_h);

  for (int i = 0; i < NDEPTH; ++i) {
    const float* xsrc = (i == 0) ? x_in : xw32;

    TDs5 td;
    td.d[0] = { wq   + (size_t)i*589824,  wqT,   768,  768,    0, 0 };
    td.d[1] = { wkv  + (size_t)i*1179648, wkvT,  768, 1536,  576, 0 };
    td.d[2] = { wo   + (size_t)i*589824,  woT,   768,  768, 1728, 0 };
    td.d[3] = { wff1 + (size_t)i*3145728, wff1T, 768, 4096, 2304, 1 };
    td.d[4] = { wff2 + (size_t)i*1572864, wff2T, 2048, 768, 5376, 0 };
    wtrans_kernel<<<6912, 256, 0, stream>>>(td);

    // q = LN_attn(x) @ wq ; k,v = x @ wkv (k compact, v transposed in-epilogue)
    qkv_kernel<<<dim3(12,32,2), 256, 0, stream>>>(S_h, xw16, wqT, wkvT, qbuf, kbuf, vtb);
    // rope(q,k) + l2norm + scale (8 folded into q)
    rope_kernel<<<ROWS, 384, 0, stream>>>(qbuf, kbuf, q_scale + i*DH, k_scale + i*DH, qhb, khb);
    attn_kernel<<<dim3(16,48), 256, 0, stream>>>(qhb, khb, vtb,
                                                 q_scale + i*DH, k_scale + i*DH, S_h);
    // x = x + o @ wo (split-K=2) ; fused reduce + residual + ff-LN
    gemm_splitk_kernel<64,384,768><<<dim3(12,32,2), 256, 0, stream>>>(S_h, woT, wP, ROWS, DIM);
    redln_kernel<<<ROWS, 256, 0, stream>>>(wP, wP + E, xsrc, xw32, nullptr, nullptr,
                                           ff_gamma + i*DIM, ff_beta + i*DIM, S_h);
    // gl = a*gelu(g) fused in FF1 epilogue (256^2 2-phase kernel)
    gemm256_kernel<<<dim3(16,16), 512, 0, stream>>>(S_h, wff1T, glbuf, ROWS, 2*FFI);
    // x = x + gl @ wff2 (split-K=2) ; fused reduce + residual (+ next attn-LN)
    gemm_splitk_kernel<64,1024,2048><<<dim3(12,32,2), 256, 0, stream>>>(glbuf, wff2T, fP, ROWS, DIM);
    if (i < NDEPTH-1)
      redln_kernel<<<ROWS, 256, 0, stream>>>(fP, fP + E, xw32, xw32, xw16, nullptr,
                                             attn_gamma + (i+1)*DIM, nullptr, S_h);
    else
      redln_kernel<<<ROWS, 256, 0, stream>>>(fP, fP + E, xw32, nullptr, nullptr, outp,
                                             nullptr, nullptr, nullptr);
  }
}